// Round 4
// baseline (486.751 us; speedup 1.0000x reference)
//
#include <hip/hip_runtime.h>
#include <stdint.h>

// ---------------------------------------------------------------------------
// StructureAE: h = x@W ; GAT edge softmax aggregate ; embed = leaky(out) ;
// recon = sigmoid(embed @ embed^T)
// N=10000, in_dim=512, out_dim=128, E=320000 (+N self loops)
// d_out = [recon (N*N f32), embed (N*128 f32)]
// ---------------------------------------------------------------------------

typedef __attribute__((ext_vector_type(8))) short short8v;  // 8 bf16 (4 VGPR)
typedef __attribute__((ext_vector_type(4))) float f32x4;

#define IN_DIM 512
#define OUT_DIM 128
#define NEG_ATT 0.5f
#define NEG_ACT 0.01f

__device__ __forceinline__ float leakyf(float v, float s) { return v >= 0.f ? v : s * v; }

__device__ __forceinline__ uint16_t f2bf(float v) {
  uint32_t u = __float_as_uint(v);
  u += 0x7FFFu + ((u >> 16) & 1u);   // round-to-nearest-even
  return (uint16_t)(u >> 16);
}
__device__ __forceinline__ float bf2f(uint16_t b) { return __uint_as_float(((uint32_t)b) << 16); }

// ---------------- h = x @ W  (f32, 16-row tile, fused att dots) -------------
__global__ __launch_bounds__(256) void k_h_gemm(const float* __restrict__ x,
                                                const float* __restrict__ W,
                                                const float* __restrict__ att_s_g,
                                                const float* __restrict__ att_d_g,
                                                float* __restrict__ h,
                                                float* __restrict__ a_src,
                                                float* __restrict__ a_dst, int N) {
  __shared__ float sX[16][68];    // +4 pad
  __shared__ float sW[64][128];   // 32 KB
  int tid = threadIdx.x;
  int rowBase = blockIdx.x * 16;
  int tx = tid & 31, ty = tid >> 5;   // 32 col-groups x 8 row-groups (2 rows each)
  float acc[2][4] = {};
  for (int kt = 0; kt < IN_DIM / 64; ++kt) {
    {
      int r = tid >> 4, c4 = tid & 15;   // 16 rows x 16 float4
      int gr = rowBase + r;
      float4 v = make_float4(0.f, 0.f, 0.f, 0.f);
      if (gr < N) v = *(const float4*)&x[(size_t)gr * IN_DIM + kt * 64 + c4 * 4];
      *(float4*)&sX[r][c4 * 4] = v;
    }
    #pragma unroll
    for (int i = 0; i < 8; ++i) {        // 64x128 = 2048 float4
      int idx = tid + i * 256;
      int wr = idx >> 5, wc4 = idx & 31;
      *(float4*)&sW[wr][wc4 * 4] = *(const float4*)&W[(size_t)(kt * 64 + wr) * OUT_DIM + wc4 * 4];
    }
    __syncthreads();
    for (int k = 0; k < 64; k += 4) {
      float4 wreg[4];
      #pragma unroll
      for (int kk = 0; kk < 4; ++kk) wreg[kk] = *(const float4*)&sW[k + kk][tx * 4];
      #pragma unroll
      for (int i = 0; i < 2; ++i) {
        float4 xr = *(const float4*)&sX[ty * 2 + i][k];
        const float* xv = (const float*)&xr;
        #pragma unroll
        for (int kk = 0; kk < 4; ++kk) {
          acc[i][0] = fmaf(xv[kk], wreg[kk].x, acc[i][0]);
          acc[i][1] = fmaf(xv[kk], wreg[kk].y, acc[i][1]);
          acc[i][2] = fmaf(xv[kk], wreg[kk].z, acc[i][2]);
          acc[i][3] = fmaf(xv[kk], wreg[kk].w, acc[i][3]);
        }
      }
    }
    __syncthreads();
  }
  float atts[4], attd[4];
  #pragma unroll
  for (int j = 0; j < 4; ++j) { atts[j] = att_s_g[tx * 4 + j]; attd[j] = att_d_g[tx * 4 + j]; }
  #pragma unroll
  for (int i = 0; i < 2; ++i) {
    int row = rowBase + ty * 2 + i;
    float ps = 0.f, pd = 0.f;
    #pragma unroll
    for (int j = 0; j < 4; ++j) { ps = fmaf(acc[i][j], atts[j], ps); pd = fmaf(acc[i][j], attd[j], pd); }
    #pragma unroll
    for (int off = 16; off; off >>= 1) {   // reduce across the 32 tx lanes
      ps += __shfl_xor(ps, off);
      pd += __shfl_xor(pd, off);
    }
    if (row < N) {
      float4 v = make_float4(acc[i][0], acc[i][1], acc[i][2], acc[i][3]);
      *(float4*)&h[(size_t)row * OUT_DIM + tx * 4] = v;
      if (tx == 0) { a_src[row] = ps; a_dst[row] = pd; }
    }
  }
}

// ---------------- CSR build --------------------------------------------------
__global__ void k_zero(int* __restrict__ p, int n) {
  int i = blockIdx.x * blockDim.x + threadIdx.x;
  if (i < n) p[i] = 0;
}
__global__ void k_count(const int* __restrict__ dst, int* __restrict__ cnt, int E) {
  int e = blockIdx.x * blockDim.x + threadIdx.x;
  if (e < E) atomicAdd(&cnt[dst[e]], 1);
}
__global__ __launch_bounds__(1024) void k_scan(const int* __restrict__ cnt,
                                               int* __restrict__ row_start, int N) {
  __shared__ int sd[1024];
  int t = threadIdx.x;
  const int CH = (N + 1023) >> 10;
  int base = t * CH;
  int s = 0;
  for (int k = 0; k < CH; ++k) { int i = base + k; if (i < N) s += cnt[i]; }
  sd[t] = s;
  __syncthreads();
  for (int off = 1; off < 1024; off <<= 1) {
    int v = (t >= off) ? sd[t - off] : 0;
    __syncthreads();
    sd[t] += v;
    __syncthreads();
  }
  int run = (t == 0) ? 0 : sd[t - 1];
  for (int k = 0; k < CH; ++k) {
    int i = base + k;
    if (i < N) { row_start[i] = run; run += cnt[i]; }
  }
  if (t == 1023) row_start[N] = sd[1023];
}
__global__ void k_copy(const int* __restrict__ a, int* __restrict__ b, int n) {
  int i = blockIdx.x * blockDim.x + threadIdx.x;
  if (i < n) b[i] = a[i];
}
__global__ void k_fill(const int* __restrict__ src, const int* __restrict__ dst,
                       int* __restrict__ cursor, int* __restrict__ csr, int E) {
  int e = blockIdx.x * blockDim.x + threadIdx.x;
  if (e < E) {
    int d = dst[e];
    int pos = atomicAdd(&cursor[d], 1);
    csr[pos] = src[e];
  }
}

// ---------------- zero bf16 pad rows ----------------------------------------
__global__ void k_pad(uint16_t* __restrict__ ehi, uint16_t* __restrict__ elo,
                      int N, int NPAD) {
  int total = (NPAD - N) * OUT_DIM;
  for (int i = threadIdx.x + blockIdx.x * blockDim.x; i < total; i += blockDim.x * gridDim.x) {
    ehi[(size_t)N * OUT_DIM + i] = 0;
    elo[(size_t)N * OUT_DIM + i] = 0;
  }
}

// ---------------- per-dst softmax aggregation (one wave per node) -----------
__global__ __launch_bounds__(256) void k_aggregate(
    const float* __restrict__ h, const float* __restrict__ a_src,
    const float* __restrict__ a_dst, const int* __restrict__ row_start,
    const int* __restrict__ csr, const float* __restrict__ bias,
    float* __restrict__ embed_out, uint16_t* __restrict__ ehi,
    uint16_t* __restrict__ elo, int N) {
  int wid = (int)((blockIdx.x * blockDim.x + threadIdx.x) >> 6);
  int lane = threadIdx.x & 63;
  if (wid >= N) return;
  int i = wid;
  int s0 = row_start[i], s1 = row_start[i + 1];
  float adst = a_dst[i];
  float eself = leakyf(a_src[i] + adst, NEG_ATT);
  float m = eself;
  for (int k = s0 + lane; k < s1; k += 64) {
    float e = leakyf(a_src[csr[k]] + adst, NEG_ATT);
    m = fmaxf(m, e);
  }
  #pragma unroll
  for (int off = 32; off; off >>= 1) m = fmaxf(m, __shfl_xor(m, off));
  float dsum = 0.f;
  for (int k = s0 + lane; k < s1; k += 64) {
    float e = leakyf(a_src[csr[k]] + adst, NEG_ATT);
    dsum += __expf(e - m);
  }
  #pragma unroll
  for (int off = 32; off; off >>= 1) dsum += __shfl_xor(dsum, off);
  dsum += __expf(eself - m);
  float inv = 1.0f / dsum;
  float wself = __expf(eself - m) * inv;
  float acc0 = h[(size_t)i * OUT_DIM + lane] * wself;
  float acc1 = h[(size_t)i * OUT_DIM + 64 + lane] * wself;
  #pragma unroll 4
  for (int k = s0; k < s1; ++k) {
    int s = csr[k];  // uniform across wave
    float w = __expf(leakyf(a_src[s] + adst, NEG_ATT) - m) * inv;
    acc0 = fmaf(h[(size_t)s * OUT_DIM + lane], w, acc0);
    acc1 = fmaf(h[(size_t)s * OUT_DIM + 64 + lane], w, acc1);
  }
  float o0 = leakyf(acc0 + bias[lane], NEG_ACT);
  float o1 = leakyf(acc1 + bias[64 + lane], NEG_ACT);
  embed_out[(size_t)i * OUT_DIM + lane] = o0;
  embed_out[(size_t)i * OUT_DIM + 64 + lane] = o1;
  uint16_t h0 = f2bf(o0), h1 = f2bf(o1);
  uint16_t l0 = f2bf(o0 - bf2f(h0)), l1 = f2bf(o1 - bf2f(h1));
  ehi[(size_t)i * OUT_DIM + lane] = h0;
  ehi[(size_t)i * OUT_DIM + 64 + lane] = h1;
  elo[(size_t)i * OUT_DIM + lane] = l0;
  elo[(size_t)i * OUT_DIM + 64 + lane] = l1;
}

// ---------------- recon = sigmoid(embed @ embed^T) via bf16-split MFMA ------
// Block: 512 thr = 8 waves (2 row x 4 col), tile 128x256, wave = 64x64
// (acc[4][4] = 64 acc regs -> ~120 unified -> 4 waves/SIMD, 2 blocks/CU).
// Epilogue: two 64-row LDS slices; store instr = ONE row x 1024 B contiguous
// (full 128B lines except misphased-row tile edges). 3 barriers total,
// covered by the co-resident block.
// XCD 2D chunking: 80x40 panel grid -> 8 chunks of 20x20 (one per XCD);
// per-XCD working set = 1.3 MB A + 2.6 MB B < 4 MB L2.
// mfma_f32_16x16x32_bf16 A/B: lane holds row/col = lane&15, k = 8*(lane>>4)+j;
// C/D: col = lane&15, row = (lane>>4)*4 + reg.
__global__ __launch_bounds__(512, 4) void k_recon(const uint16_t* __restrict__ ehi,
                                                  const uint16_t* __restrict__ elo,
                                                  float* __restrict__ out,
                                                  int N, int nbR, int nbC) {
  __shared__ float sOut[64][260];   // 66560 B (rows 16B-aligned: 260*4=1040)
  int tid = threadIdx.x;
  int wid = tid >> 6, lane = tid & 63;
  int wr = wid >> 2, wc = wid & 3;   // 2 x 4 waves
  int r16 = lane & 15, kg = lane >> 4;

  int orig = blockIdx.x;
  int by, bx;
  if (nbR == 80 && nbC == 40) {
    int xcd = orig & 7, idx = orig >> 3;       // assume round-robin XCD dispatch
    int cy = xcd >> 1, cx = xcd & 1;           // 4x2 chunk grid
    int ly = idx / 20, lx = idx - ly * 20;     // 20x20 panels per chunk
    by = cy * 20 + ly;
    bx = cx * 20 + lx;
  } else {
    by = orig / nbC;
    bx = orig - by * nbC;
  }
  int rowBlk = by * 128, colBlk = bx * 256;
  int rowW = rowBlk + wr * 64;
  int colW = colBlk + wc * 64;

  f32x4 acc[4][4];
  #pragma unroll
  for (int a = 0; a < 4; ++a)
    #pragma unroll
    for (int b = 0; b < 4; ++b) acc[a][b] = (f32x4){0.f, 0.f, 0.f, 0.f};

  #pragma unroll
  for (int kc = 0; kc < 4; ++kc) {   // 4 chunks of K=32
    int kOff = kc * 32 + kg * 8;
    short8v bfr[4];
    // phase 1: B = hi, A = hi & lo
    #pragma unroll
    for (int tj = 0; tj < 4; ++tj)
      bfr[tj] = *(const short8v*)&ehi[(size_t)(colW + tj * 16 + r16) * OUT_DIM + kOff];
    #pragma unroll
    for (int ti = 0; ti < 4; ++ti) {
      size_t ao = (size_t)(rowW + ti * 16 + r16) * OUT_DIM + kOff;
      short8v ah = *(const short8v*)&ehi[ao];
      short8v al = *(const short8v*)&elo[ao];
      #pragma unroll
      for (int tj = 0; tj < 4; ++tj) {
        acc[ti][tj] = __builtin_amdgcn_mfma_f32_16x16x32_bf16(ah, bfr[tj], acc[ti][tj], 0, 0, 0);
        acc[ti][tj] = __builtin_amdgcn_mfma_f32_16x16x32_bf16(al, bfr[tj], acc[ti][tj], 0, 0, 0);
      }
    }
    // phase 2: B = lo, A = hi
    #pragma unroll
    for (int tj = 0; tj < 4; ++tj)
      bfr[tj] = *(const short8v*)&elo[(size_t)(colW + tj * 16 + r16) * OUT_DIM + kOff];
    #pragma unroll
    for (int ti = 0; ti < 4; ++ti) {
      size_t ao = (size_t)(rowW + ti * 16 + r16) * OUT_DIM + kOff;
      short8v ah = *(const short8v*)&ehi[ao];
      #pragma unroll
      for (int tj = 0; tj < 4; ++tj)
        acc[ti][tj] = __builtin_amdgcn_mfma_f32_16x16x32_bf16(ah, bfr[tj], acc[ti][tj], 0, 0, 0);
    }
  }

  bool colFull = (colBlk + 255 < N);
  #pragma unroll
  for (int s = 0; s < 2; ++s) {
    // owning row-wave group deposits its 64x256 slice (2-way bank alias: free)
    if (wr == s) {
      #pragma unroll
      for (int ti = 0; ti < 4; ++ti)
        #pragma unroll
        for (int tj = 0; tj < 4; ++tj)
          #pragma unroll
          for (int q = 0; q < 4; ++q)
            sOut[ti * 16 + kg * 4 + q][wc * 64 + tj * 16 + r16] = acc[ti][tj][q];
    }
    __syncthreads();
    int srow0 = rowBlk + s * 64;
    #pragma unroll
    for (int p = 0; p < 8; ++p) {
      int idx2 = tid + p * 512;            // 4096 f32x4 per slice
      int row = idx2 >> 6, c4 = idx2 & 63; // wave-uniform row, 1024 B/instr
      f32x4 v = *(const f32x4*)&sOut[row][c4 * 4];
      #pragma unroll
      for (int j = 0; j < 4; ++j) v[j] = 1.0f / (1.0f + __expf(-v[j]));
      int rr = srow0 + row;
      int c = colBlk + c4 * 4;
      if (rr < N) {
        if (colFull || c + 3 < N) {
          __builtin_nontemporal_store(v, (f32x4*)&out[(size_t)rr * N + c]);
        } else {
          #pragma unroll
          for (int j = 0; j < 4; ++j)
            if (c + j < N) __builtin_nontemporal_store(v[j], &out[(size_t)rr * N + c + j]);
        }
      }
    }
    if (s == 0) __syncthreads();
  }
}

// ---------------------------------------------------------------------------
extern "C" void kernel_launch(void* const* d_in, const int* in_sizes, int n_in,
                              void* d_out, int out_size, void* d_ws, size_t ws_size,
                              hipStream_t stream) {
  const float* x = (const float*)d_in[0];
  const int* ei = (const int*)d_in[1];
  const float* W = (const float*)d_in[2];
  const float* att_s = (const float*)d_in[3];
  const float* att_d = (const float*)d_in[4];
  const float* bias = (const float*)d_in[5];

  const int N = in_sizes[0] / IN_DIM;   // 10000
  const int E = in_sizes[1] / 2;        // 320000
  const int NP2 = ((N + 255) / 256) * 256;   // 10240

  float* out = (float*)d_out;
  float* embed_out = out + (size_t)N * N;

  // workspace layout (16B-aligned at ehi)
  float* h = (float*)d_ws;                      // N*128 f32
  float* a_src = h + (size_t)N * OUT_DIM;       // N
  float* a_dst = a_src + N;                     // N
  int* cnt = (int*)(a_dst + N);                 // N
  int* row_start = cnt + N;                     // N+4 (padded)
  int* cursor = row_start + (N + 4);            // N
  int* csr = cursor + N;                        // E
  uint16_t* ehi = (uint16_t*)(csr + E);         // NP2*128 bf16
  uint16_t* elo = ehi + (size_t)NP2 * OUT_DIM;  // NP2*128 bf16

  const int* e_src = ei;
  const int* e_dst = ei + E;

  k_h_gemm<<<dim3((N + 15) / 16), 256, 0, stream>>>(x, W, att_s, att_d, h, a_src, a_dst, N);
  k_zero<<<dim3((N + 255) / 256), 256, 0, stream>>>(cnt, N);
  k_count<<<dim3((E + 255) / 256), 256, 0, stream>>>(e_dst, cnt, E);
  k_scan<<<dim3(1), 1024, 0, stream>>>(cnt, row_start, N);
  k_copy<<<dim3((N + 255) / 256), 256, 0, stream>>>(row_start, cursor, N);
  k_fill<<<dim3((E + 255) / 256), 256, 0, stream>>>(e_src, e_dst, cursor, csr, E);
  k_pad<<<dim3(8), 256, 0, stream>>>(ehi, elo, N, NP2);
  k_aggregate<<<dim3((N * 64 + 255) / 256), 256, 0, stream>>>(
      h, a_src, a_dst, row_start, csr, bias, embed_out, ehi, elo, N);
  const int nbR = NP2 / 128;   // 80
  const int nbC = NP2 / 256;   // 40
  k_recon<<<dim3(nbR * nbC), 512, 0, stream>>>(ehi, elo, out, N, nbR, nbC);
}

// Round 5
// 247.659 us; speedup vs baseline: 1.9654x; 1.9654x over previous
//
#include <hip/hip_runtime.h>
#include <stdint.h>

// ---------------------------------------------------------------------------
// StructureAE: h = x@W ; GAT edge softmax aggregate ; embed = leaky(out) ;
// recon = sigmoid(embed @ embed^T)
// N=10000, in_dim=512, out_dim=128, E=320000 (+N self loops)
// d_out = [recon (N*N f32), embed (N*128 f32)]
// ---------------------------------------------------------------------------

typedef __attribute__((ext_vector_type(8))) short short8v;  // 8 bf16 (4 VGPR)
typedef __attribute__((ext_vector_type(4))) float f32x4;

#define IN_DIM 512
#define OUT_DIM 128
#define NEG_ATT 0.5f
#define NEG_ACT 0.01f

__device__ __forceinline__ float leakyf(float v, float s) { return v >= 0.f ? v : s * v; }

__device__ __forceinline__ uint16_t f2bf(float v) {
  uint32_t u = __float_as_uint(v);
  u += 0x7FFFu + ((u >> 16) & 1u);   // round-to-nearest-even
  return (uint16_t)(u >> 16);
}

// ---------------- h = x @ W (f32, no LDS) + fused att dots ------------------
// 256 thr: tx = 32 col-groups (4 f32 each), ty = 8 row-groups x 4 rows.
// W rows read coalesced (512 B per 32-lane group, L1/L2-resident);
// x reads are wave-broadcast (all tx lanes same 16 B). Pure FMA-bound.
__global__ __launch_bounds__(256) void k_h_gemm(const float* __restrict__ x,
                                                const float* __restrict__ W,
                                                const float* __restrict__ att_s_g,
                                                const float* __restrict__ att_d_g,
                                                float* __restrict__ h,
                                                float* __restrict__ a_src,
                                                float* __restrict__ a_dst, int N) {
  int tid = threadIdx.x;
  int tx = tid & 31, ty = tid >> 5;
  int row0 = blockIdx.x * 32 + ty * 4;
  int rc[4];
  #pragma unroll
  for (int r = 0; r < 4; ++r) rc[r] = (row0 + r < N) ? (row0 + r) : (N - 1);

  f32x4 acc[4];
  #pragma unroll
  for (int r = 0; r < 4; ++r) acc[r] = (f32x4){0.f, 0.f, 0.f, 0.f};

  for (int k = 0; k < IN_DIM; k += 4) {
    f32x4 wreg[4];
    #pragma unroll
    for (int kk = 0; kk < 4; ++kk)
      wreg[kk] = *(const f32x4*)&W[(size_t)(k + kk) * OUT_DIM + tx * 4];
    #pragma unroll
    for (int r = 0; r < 4; ++r) {
      f32x4 xv = *(const f32x4*)&x[(size_t)rc[r] * IN_DIM + k];
      #pragma unroll
      for (int kk = 0; kk < 4; ++kk) {
        acc[r][0] = fmaf(xv[kk], wreg[kk][0], acc[r][0]);
        acc[r][1] = fmaf(xv[kk], wreg[kk][1], acc[r][1]);
        acc[r][2] = fmaf(xv[kk], wreg[kk][2], acc[r][2]);
        acc[r][3] = fmaf(xv[kk], wreg[kk][3], acc[r][3]);
      }
    }
  }

  float atts[4], attd[4];
  #pragma unroll
  for (int j = 0; j < 4; ++j) { atts[j] = att_s_g[tx * 4 + j]; attd[j] = att_d_g[tx * 4 + j]; }
  #pragma unroll
  for (int r = 0; r < 4; ++r) {
    int row = row0 + r;
    float ps = 0.f, pd = 0.f;
    #pragma unroll
    for (int j = 0; j < 4; ++j) { ps = fmaf(acc[r][j], atts[j], ps); pd = fmaf(acc[r][j], attd[j], pd); }
    #pragma unroll
    for (int off = 16; off; off >>= 1) {   // reduce across the 32 tx lanes
      ps += __shfl_xor(ps, off);
      pd += __shfl_xor(pd, off);
    }
    if (row < N) {
      *(f32x4*)&h[(size_t)row * OUT_DIM + tx * 4] = acc[r];
      if (tx == 0) { a_src[row] = ps; a_dst[row] = pd; }
    }
  }
}

// ---------------- CSR build --------------------------------------------------
__global__ void k_zero(int* __restrict__ p, int n) {
  int i = blockIdx.x * blockDim.x + threadIdx.x;
  if (i < n) p[i] = 0;
}
__global__ void k_count(const int* __restrict__ dst, int* __restrict__ cnt, int E) {
  int e = blockIdx.x * blockDim.x + threadIdx.x;
  if (e < E) atomicAdd(&cnt[dst[e]], 1);
}
__global__ __launch_bounds__(1024) void k_scan(const int* __restrict__ cnt,
                                               int* __restrict__ row_start, int N) {
  __shared__ int sd[1024];
  int t = threadIdx.x;
  const int CH = (N + 1023) >> 10;
  int base = t * CH;
  int s = 0;
  for (int k = 0; k < CH; ++k) { int i = base + k; if (i < N) s += cnt[i]; }
  sd[t] = s;
  __syncthreads();
  for (int off = 1; off < 1024; off <<= 1) {
    int v = (t >= off) ? sd[t - off] : 0;
    __syncthreads();
    sd[t] += v;
    __syncthreads();
  }
  int run = (t == 0) ? 0 : sd[t - 1];
  for (int k = 0; k < CH; ++k) {
    int i = base + k;
    if (i < N) { row_start[i] = run; run += cnt[i]; }
  }
  if (t == 1023) row_start[N] = sd[1023];
}
__global__ void k_copy(const int* __restrict__ a, int* __restrict__ b, int n) {
  int i = blockIdx.x * blockDim.x + threadIdx.x;
  if (i < n) b[i] = a[i];
}
__global__ void k_fill(const int* __restrict__ src, const int* __restrict__ dst,
                       int* __restrict__ cursor, int* __restrict__ csr, int E) {
  int e = blockIdx.x * blockDim.x + threadIdx.x;
  if (e < E) {
    int d = dst[e];
    int pos = atomicAdd(&cursor[d], 1);
    csr[pos] = src[e];
  }
}

// ---------------- zero bf16 pad rows ----------------------------------------
__global__ void k_pad(uint16_t* __restrict__ ebf, int N, int NPAD) {
  int total = (NPAD - N) * OUT_DIM;
  for (int i = threadIdx.x + blockIdx.x * blockDim.x; i < total; i += blockDim.x * gridDim.x)
    ebf[(size_t)N * OUT_DIM + i] = 0;
}

// ---------------- per-dst softmax aggregation (one wave per node) -----------
__global__ __launch_bounds__(256) void k_aggregate(
    const float* __restrict__ h, const float* __restrict__ a_src,
    const float* __restrict__ a_dst, const int* __restrict__ row_start,
    const int* __restrict__ csr, const float* __restrict__ bias,
    float* __restrict__ embed_out, uint16_t* __restrict__ ebf, int N) {
  int wid = (int)((blockIdx.x * blockDim.x + threadIdx.x) >> 6);
  int lane = threadIdx.x & 63;
  if (wid >= N) return;
  int i = wid;
  int s0 = row_start[i], s1 = row_start[i + 1];
  float adst = a_dst[i];
  float eself = leakyf(a_src[i] + adst, NEG_ATT);
  float m = eself;
  for (int k = s0 + lane; k < s1; k += 64) {
    float e = leakyf(a_src[csr[k]] + adst, NEG_ATT);
    m = fmaxf(m, e);
  }
  #pragma unroll
  for (int off = 32; off; off >>= 1) m = fmaxf(m, __shfl_xor(m, off));
  float dsum = 0.f;
  for (int k = s0 + lane; k < s1; k += 64) {
    float e = leakyf(a_src[csr[k]] + adst, NEG_ATT);
    dsum += __expf(e - m);
  }
  #pragma unroll
  for (int off = 32; off; off >>= 1) dsum += __shfl_xor(dsum, off);
  dsum += __expf(eself - m);
  float inv = 1.0f / dsum;
  float wself = __expf(eself - m) * inv;
  float acc0 = h[(size_t)i * OUT_DIM + lane] * wself;
  float acc1 = h[(size_t)i * OUT_DIM + 64 + lane] * wself;
  #pragma unroll 4
  for (int k = s0; k < s1; ++k) {
    int s = csr[k];  // uniform across wave
    float w = __expf(leakyf(a_src[s] + adst, NEG_ATT) - m) * inv;
    acc0 = fmaf(h[(size_t)s * OUT_DIM + lane], w, acc0);
    acc1 = fmaf(h[(size_t)s * OUT_DIM + 64 + lane], w, acc1);
  }
  float o0 = leakyf(acc0 + bias[lane], NEG_ACT);
  float o1 = leakyf(acc1 + bias[64 + lane], NEG_ACT);
  embed_out[(size_t)i * OUT_DIM + lane] = o0;
  embed_out[(size_t)i * OUT_DIM + 64 + lane] = o1;
  ebf[(size_t)i * OUT_DIM + lane] = f2bf(o0);
  ebf[(size_t)i * OUT_DIM + 64 + lane] = f2bf(o1);
}

// ---------------- recon = sigmoid(embed @ embed^T), LDS-staged MFMA ---------
// 128x128 tile, 512 thr = 8 waves (2 row x 4 col), wave = 64x32.
// Stage A,B tiles (32 KB each) into LDS via coalesced reg-staging with
// XOR swizzle (slot ^= row&7) -> conflict-free ds_read_b128 fragments.
// sOut epilogue slab ALIASES the stage buffers after the MFMA barrier:
// 65 KB LDS total -> 2 blocks/CU (16 waves/CU); co-resident block's compute
// overlaps this block's store stream. Stores: 512 B contiguous row segments,
// nontemporal. Single bf16 term (no hi/lo split).
// mfma_f32_16x16x32_bf16 A/B: lane holds row/col = lane&15, k = 8*(lane>>4)+j;
// C/D: col = lane&15, row = (lane>>4)*4 + reg.
__global__ __launch_bounds__(512, 4) void k_recon(const uint16_t* __restrict__ ebf,
                                                  float* __restrict__ out,
                                                  int N, int nb) {
  __shared__ __align__(16) unsigned char smem[66560];
  uint16_t* sA = (uint16_t*)smem;            // [128][128] bf16, swizzled
  uint16_t* sB = (uint16_t*)(smem + 32768);  // [128][128] bf16, swizzled
  float* sO = (float*)smem;                  // [64][133] f32 (aliases sA/sB)

  int tid = threadIdx.x;
  int wid = tid >> 6, lane = tid & 63;
  int wr = wid >> 2, wc = wid & 3;
  int r16 = lane & 15, kg = lane >> 4;

  // bijective XCD swizzle (m204): round-robin dispatch -> per-XCD contiguous
  // tile range in row-panel-major order; B panel (2.6 MB) stays L2-resident.
  int nwg = nb * nb;
  int q = nwg >> 3, r8 = nwg & 7;
  int orig = blockIdx.x;
  int xcd = orig & 7, sub = orig >> 3;
  int swz = (xcd < r8 ? xcd * (q + 1) : r8 * (q + 1) + (xcd - r8) * q) + sub;
  int by = swz / nb, bx = swz - by * nb;
  int rowBlk = by * 128, colBlk = bx * 128;

  // ---- stage A and B tiles (reg-staged, swizzled ds_write) ----
  #pragma unroll
  for (int p = 0; p < 4; ++p) {
    int i2 = p * 512 + tid;          // 2048 x 16B chunks per tile
    int row = i2 >> 4, slot = i2 & 15;
    f32x4 va = *(const f32x4*)&ebf[(size_t)(rowBlk + row) * OUT_DIM + slot * 8];
    f32x4 vb = *(const f32x4*)&ebf[(size_t)(colBlk + row) * OUT_DIM + slot * 8];
    int ss = slot ^ (row & 7);
    *(f32x4*)&sA[row * OUT_DIM + ss * 8] = va;
    *(f32x4*)&sB[row * OUT_DIM + ss * 8] = vb;
  }
  __syncthreads();

  // ---- MFMA: wave computes 64x32, K=128 in 4 chunks of 32 ----
  int rowWl = wr * 64, colWl = wc * 32;
  f32x4 acc[4][2];
  #pragma unroll
  for (int a = 0; a < 4; ++a)
    #pragma unroll
    for (int b = 0; b < 2; ++b) acc[a][b] = (f32x4){0.f, 0.f, 0.f, 0.f};

  #pragma unroll
  for (int kc = 0; kc < 4; ++kc) {
    short8v bfr[2];
    #pragma unroll
    for (int tj = 0; tj < 2; ++tj) {
      int rw = colWl + tj * 16 + r16;
      int ss = (kc * 4 + kg) ^ (rw & 7);
      bfr[tj] = *(const short8v*)&sB[rw * OUT_DIM + ss * 8];
    }
    #pragma unroll
    for (int ti = 0; ti < 4; ++ti) {
      int rw = rowWl + ti * 16 + r16;
      int ss = (kc * 4 + kg) ^ (rw & 7);
      short8v af = *(const short8v*)&sA[rw * OUT_DIM + ss * 8];
      #pragma unroll
      for (int tj = 0; tj < 2; ++tj)
        acc[ti][tj] = __builtin_amdgcn_mfma_f32_16x16x32_bf16(af, bfr[tj], acc[ti][tj], 0, 0, 0);
    }
  }

  // ---- epilogue: 2 slices of 64 rows via sO (aliases stage LDS) ----
  bool colFull = (colBlk + 128 <= N);
  #pragma unroll
  for (int s = 0; s < 2; ++s) {
    __syncthreads();   // s=0: all MFMA ds_reads done; s=1: slice-0 reads done
    if (wr == s) {
      #pragma unroll
      for (int ti = 0; ti < 4; ++ti)
        #pragma unroll
        for (int tj = 0; tj < 2; ++tj)
          #pragma unroll
          for (int qq = 0; qq < 4; ++qq)
            sO[(ti * 16 + kg * 4 + qq) * 133 + wc * 32 + tj * 16 + r16] = acc[ti][tj][qq];
    }
    __syncthreads();
    int srow0 = rowBlk + s * 64;
    #pragma unroll
    for (int p = 0; p < 4; ++p) {
      int i2 = p * 512 + tid;
      int row = i2 >> 5, c = i2 & 31;   // 32 lanes x 16B = 512 B per row segment
      f32x4 v = *(const f32x4*)&sO[row * 133 + c * 4];
      #pragma unroll
      for (int j = 0; j < 4; ++j) v[j] = 1.0f / (1.0f + __expf(-v[j]));
      int rr = srow0 + row;
      if (rr < N) {
        int col = colBlk + c * 4;
        if (colFull) {
          __builtin_nontemporal_store(v, (f32x4*)&out[(size_t)rr * N + col]);
        } else {
          #pragma unroll
          for (int j = 0; j < 4; ++j)
            if (col + j < N) __builtin_nontemporal_store(v[j], &out[(size_t)rr * N + col + j]);
        }
      }
    }
  }
}

// ---------------------------------------------------------------------------
extern "C" void kernel_launch(void* const* d_in, const int* in_sizes, int n_in,
                              void* d_out, int out_size, void* d_ws, size_t ws_size,
                              hipStream_t stream) {
  const float* x = (const float*)d_in[0];
  const int* ei = (const int*)d_in[1];
  const float* W = (const float*)d_in[2];
  const float* att_s = (const float*)d_in[3];
  const float* att_d = (const float*)d_in[4];
  const float* bias = (const float*)d_in[5];

  const int N = in_sizes[0] / IN_DIM;        // 10000
  const int E = in_sizes[1] / 2;             // 320000
  const int NB = (N + 127) / 128;            // 79
  const int NPAD = NB * 128;                 // 10112

  float* out = (float*)d_out;
  float* embed_out = out + (size_t)N * N;

  // workspace layout (all segments 16B-aligned)
  float* h = (float*)d_ws;                      // N*128 f32
  float* a_src = h + (size_t)N * OUT_DIM;       // N
  float* a_dst = a_src + N;                     // N
  int* cnt = (int*)(a_dst + N);                 // N
  int* row_start = cnt + N;                     // N+4 (padded)
  int* cursor = row_start + (N + 4);            // N
  int* csr = cursor + N;                        // E
  uint16_t* ebf = (uint16_t*)(csr + E);         // NPAD*128 bf16

  const int* e_src = ei;
  const int* e_dst = ei + E;

  k_h_gemm<<<dim3((N + 31) / 32), 256, 0, stream>>>(x, W, att_s, att_d, h, a_src, a_dst, N);
  k_zero<<<dim3((N + 255) / 256), 256, 0, stream>>>(cnt, N);
  k_count<<<dim3((E + 255) / 256), 256, 0, stream>>>(e_dst, cnt, E);
  k_scan<<<dim3(1), 1024, 0, stream>>>(cnt, row_start, N);
  k_copy<<<dim3((N + 255) / 256), 256, 0, stream>>>(row_start, cursor, N);
  k_fill<<<dim3((E + 255) / 256), 256, 0, stream>>>(e_src, e_dst, cursor, csr, E);
  k_pad<<<dim3(8), 256, 0, stream>>>(ebf, N, NPAD);
  k_aggregate<<<dim3((N * 64 + 255) / 256), 256, 0, stream>>>(
      h, a_src, a_dst, row_start, csr, bias, embed_out, ebf, N);
  k_recon<<<dim3(NB * NB), 512, 0, stream>>>(ebf, out, N, NB);
}

// Round 6
// 232.645 us; speedup vs baseline: 2.0922x; 1.0645x over previous
//
#include <hip/hip_runtime.h>
#include <stdint.h>

// ---------------------------------------------------------------------------
// StructureAE: h = x@W ; GAT edge softmax aggregate ; embed = leaky(out) ;
// recon = sigmoid(embed @ embed^T)
// N=10000, in_dim=512, out_dim=128, E=320000 (+N self loops)
// d_out = [recon (N*N f32), embed (N*128 f32)]
// ---------------------------------------------------------------------------

typedef __attribute__((ext_vector_type(8))) short short8v;  // 8 bf16 (4 VGPR)
typedef __attribute__((ext_vector_type(4))) float f32x4;

#define IN_DIM 512
#define OUT_DIM 128
#define NEG_ATT 0.5f
#define NEG_ACT 0.01f

__device__ __forceinline__ float leakyf(float v, float s) { return v >= 0.f ? v : s * v; }

__device__ __forceinline__ uint16_t f2bf(float v) {
  uint32_t u = __float_as_uint(v);
  u += 0x7FFFu + ((u >> 16) & 1u);   // round-to-nearest-even
  return (uint16_t)(u >> 16);
}

// ---------------- h = x @ W (f32, no LDS) + fused att dots + edge count -----
// 16 rows/block (625 blocks -> ~2.4 waves/SIMD; round-5's 313 blocks ran
// 1.2 waves/SIMD latency-exposed). tx = 32 col-groups x 4 f32; ty = 8 row
// groups x 2 rows. W rows coalesced (512 B per 32-lane group, L2-resident);
// x reads wave-broadcast. Epilogue additionally counts this block's slice of
// 512 edges into cnt (k_count fused; cnt zeroed by hipMemsetAsync upstream).
__global__ __launch_bounds__(256) void k_h_gemm(const float* __restrict__ x,
                                                const float* __restrict__ W,
                                                const float* __restrict__ att_s_g,
                                                const float* __restrict__ att_d_g,
                                                const int* __restrict__ e_dst,
                                                int* __restrict__ cnt, int E,
                                                float* __restrict__ h,
                                                float* __restrict__ a_src,
                                                float* __restrict__ a_dst, int N) {
  int tid = threadIdx.x;
  int tx = tid & 31, ty = tid >> 5;
  int row0 = blockIdx.x * 16 + ty * 2;
  int rc[2];
  #pragma unroll
  for (int r = 0; r < 2; ++r) rc[r] = (row0 + r < N) ? (row0 + r) : (N - 1);

  f32x4 acc[2];
  #pragma unroll
  for (int r = 0; r < 2; ++r) acc[r] = (f32x4){0.f, 0.f, 0.f, 0.f};

  for (int k = 0; k < IN_DIM; k += 4) {
    f32x4 wreg[4];
    #pragma unroll
    for (int kk = 0; kk < 4; ++kk)
      wreg[kk] = *(const f32x4*)&W[(size_t)(k + kk) * OUT_DIM + tx * 4];
    #pragma unroll
    for (int r = 0; r < 2; ++r) {
      f32x4 xv = *(const f32x4*)&x[(size_t)rc[r] * IN_DIM + k];
      #pragma unroll
      for (int kk = 0; kk < 4; ++kk) {
        acc[r][0] = fmaf(xv[kk], wreg[kk][0], acc[r][0]);
        acc[r][1] = fmaf(xv[kk], wreg[kk][1], acc[r][1]);
        acc[r][2] = fmaf(xv[kk], wreg[kk][2], acc[r][2]);
        acc[r][3] = fmaf(xv[kk], wreg[kk][3], acc[r][3]);
      }
    }
  }

  float atts[4], attd[4];
  #pragma unroll
  for (int j = 0; j < 4; ++j) { atts[j] = att_s_g[tx * 4 + j]; attd[j] = att_d_g[tx * 4 + j]; }
  #pragma unroll
  for (int r = 0; r < 2; ++r) {
    int row = row0 + r;
    float ps = 0.f, pd = 0.f;
    #pragma unroll
    for (int j = 0; j < 4; ++j) { ps = fmaf(acc[r][j], atts[j], ps); pd = fmaf(acc[r][j], attd[j], pd); }
    #pragma unroll
    for (int off = 16; off; off >>= 1) {   // reduce across the 32 tx lanes
      ps += __shfl_xor(ps, off);
      pd += __shfl_xor(pd, off);
    }
    if (row < N) {
      *(f32x4*)&h[(size_t)row * OUT_DIM + tx * 4] = acc[r];
      if (tx == 0) { a_src[row] = ps; a_dst[row] = pd; }
    }
  }

  // fused edge counting (this block's 512-edge slice, coalesced)
  int e0 = blockIdx.x * 512 + tid;
  if (e0 < E) atomicAdd(&cnt[e_dst[e0]], 1);
  int e1 = e0 + 256;
  if (e1 < E) atomicAdd(&cnt[e_dst[e1]], 1);
}

// ---------------- CSR build --------------------------------------------------
__global__ __launch_bounds__(1024) void k_scan(const int* __restrict__ cnt,
                                               int* __restrict__ row_start,
                                               int* __restrict__ cursor, int N) {
  __shared__ int sd[1024];
  int t = threadIdx.x;
  const int CH = (N + 1023) >> 10;
  int base = t * CH;
  int s = 0;
  for (int k = 0; k < CH; ++k) { int i = base + k; if (i < N) s += cnt[i]; }
  sd[t] = s;
  __syncthreads();
  for (int off = 1; off < 1024; off <<= 1) {
    int v = (t >= off) ? sd[t - off] : 0;
    __syncthreads();
    sd[t] += v;
    __syncthreads();
  }
  int run = (t == 0) ? 0 : sd[t - 1];
  for (int k = 0; k < CH; ++k) {
    int i = base + k;
    if (i < N) { row_start[i] = run; cursor[i] = run; run += cnt[i]; }
  }
  if (t == 1023) row_start[N] = sd[1023];
}
__global__ void k_fill(const int* __restrict__ src, const int* __restrict__ dst,
                       int* __restrict__ cursor, int* __restrict__ csr, int E) {
  int e = blockIdx.x * blockDim.x + threadIdx.x;
  if (e < E) {
    int d = dst[e];
    int pos = atomicAdd(&cursor[d], 1);
    csr[pos] = src[e];
  }
}

// ---------------- per-dst softmax aggregation (one wave per node) -----------
// Grid covers NPAD nodes: waves i in [N, NPAD) just zero their ebf row
// (k_pad fused).
__global__ __launch_bounds__(256) void k_aggregate(
    const float* __restrict__ h, const float* __restrict__ a_src,
    const float* __restrict__ a_dst, const int* __restrict__ row_start,
    const int* __restrict__ csr, const float* __restrict__ bias,
    float* __restrict__ embed_out, uint16_t* __restrict__ ebf, int N, int NPAD) {
  int wid = (int)((blockIdx.x * blockDim.x + threadIdx.x) >> 6);
  int lane = threadIdx.x & 63;
  if (wid >= N) {
    if (wid < NPAD) {
      ebf[(size_t)wid * OUT_DIM + lane] = 0;
      ebf[(size_t)wid * OUT_DIM + 64 + lane] = 0;
    }
    return;
  }
  int i = wid;
  int s0 = row_start[i], s1 = row_start[i + 1];
  float adst = a_dst[i];
  float eself = leakyf(a_src[i] + adst, NEG_ATT);
  float m = eself;
  for (int k = s0 + lane; k < s1; k += 64) {
    float e = leakyf(a_src[csr[k]] + adst, NEG_ATT);
    m = fmaxf(m, e);
  }
  #pragma unroll
  for (int off = 32; off; off >>= 1) m = fmaxf(m, __shfl_xor(m, off));
  float dsum = 0.f;
  for (int k = s0 + lane; k < s1; k += 64) {
    float e = leakyf(a_src[csr[k]] + adst, NEG_ATT);
    dsum += __expf(e - m);
  }
  #pragma unroll
  for (int off = 32; off; off >>= 1) dsum += __shfl_xor(dsum, off);
  dsum += __expf(eself - m);
  float inv = 1.0f / dsum;
  float wself = __expf(eself - m) * inv;
  float acc0 = h[(size_t)i * OUT_DIM + lane] * wself;
  float acc1 = h[(size_t)i * OUT_DIM + 64 + lane] * wself;
  #pragma unroll 4
  for (int k = s0; k < s1; ++k) {
    int s = csr[k];  // uniform across wave
    float w = __expf(leakyf(a_src[s] + adst, NEG_ATT) - m) * inv;
    acc0 = fmaf(h[(size_t)s * OUT_DIM + lane], w, acc0);
    acc1 = fmaf(h[(size_t)s * OUT_DIM + 64 + lane], w, acc1);
  }
  float o0 = leakyf(acc0 + bias[lane], NEG_ACT);
  float o1 = leakyf(acc1 + bias[64 + lane], NEG_ACT);
  embed_out[(size_t)i * OUT_DIM + lane] = o0;
  embed_out[(size_t)i * OUT_DIM + 64 + lane] = o1;
  ebf[(size_t)i * OUT_DIM + lane] = f2bf(o0);
  ebf[(size_t)i * OUT_DIM + 64 + lane] = f2bf(o1);
}

// ---------------- recon = sigmoid(embed @ embed^T), LDS-staged MFMA ---------
// (unchanged from round 5: 128x128 tile, 8 waves, XOR-swizzled LDS staging,
// sOut aliases stage buffers -> 65 KB -> 2 blocks/CU; 512 B contiguous
// nontemporal row-segment stores; single bf16 term.)
// mfma_f32_16x16x32_bf16 A/B: lane holds row/col = lane&15, k = 8*(lane>>4)+j;
// C/D: col = lane&15, row = (lane>>4)*4 + reg.
__global__ __launch_bounds__(512, 4) void k_recon(const uint16_t* __restrict__ ebf,
                                                  float* __restrict__ out,
                                                  int N, int nb) {
  __shared__ __align__(16) unsigned char smem[66560];
  uint16_t* sA = (uint16_t*)smem;            // [128][128] bf16, swizzled
  uint16_t* sB = (uint16_t*)(smem + 32768);  // [128][128] bf16, swizzled
  float* sO = (float*)smem;                  // [64][133] f32 (aliases sA/sB)

  int tid = threadIdx.x;
  int wid = tid >> 6, lane = tid & 63;
  int wr = wid >> 2, wc = wid & 3;
  int r16 = lane & 15, kg = lane >> 4;

  // bijective XCD swizzle (m204): per-XCD contiguous tile range,
  // row-panel-major; B panel (2.6 MB) stays L2-resident per XCD.
  int nwg = nb * nb;
  int q = nwg >> 3, r8 = nwg & 7;
  int orig = blockIdx.x;
  int xcd = orig & 7, sub = orig >> 3;
  int swz = (xcd < r8 ? xcd * (q + 1) : r8 * (q + 1) + (xcd - r8) * q) + sub;
  int by = swz / nb, bx = swz - by * nb;
  int rowBlk = by * 128, colBlk = bx * 128;

  // ---- stage A and B tiles (reg-staged, swizzled ds_write) ----
  #pragma unroll
  for (int p = 0; p < 4; ++p) {
    int i2 = p * 512 + tid;          // 2048 x 16B chunks per tile
    int row = i2 >> 4, slot = i2 & 15;
    f32x4 va = *(const f32x4*)&ebf[(size_t)(rowBlk + row) * OUT_DIM + slot * 8];
    f32x4 vb = *(const f32x4*)&ebf[(size_t)(colBlk + row) * OUT_DIM + slot * 8];
    int ss = slot ^ (row & 7);
    *(f32x4*)&sA[row * OUT_DIM + ss * 8] = va;
    *(f32x4*)&sB[row * OUT_DIM + ss * 8] = vb;
  }
  __syncthreads();

  // ---- MFMA: wave computes 64x32, K=128 in 4 chunks of 32 ----
  int rowWl = wr * 64, colWl = wc * 32;
  f32x4 acc[4][2];
  #pragma unroll
  for (int a = 0; a < 4; ++a)
    #pragma unroll
    for (int b = 0; b < 2; ++b) acc[a][b] = (f32x4){0.f, 0.f, 0.f, 0.f};

  #pragma unroll
  for (int kc = 0; kc < 4; ++kc) {
    short8v bfr[2];
    #pragma unroll
    for (int tj = 0; tj < 2; ++tj) {
      int rw = colWl + tj * 16 + r16;
      int ss = (kc * 4 + kg) ^ (rw & 7);
      bfr[tj] = *(const short8v*)&sB[rw * OUT_DIM + ss * 8];
    }
    #pragma unroll
    for (int ti = 0; ti < 4; ++ti) {
      int rw = rowWl + ti * 16 + r16;
      int ss = (kc * 4 + kg) ^ (rw & 7);
      short8v af = *(const short8v*)&sA[rw * OUT_DIM + ss * 8];
      #pragma unroll
      for (int tj = 0; tj < 2; ++tj)
        acc[ti][tj] = __builtin_amdgcn_mfma_f32_16x16x32_bf16(af, bfr[tj], acc[ti][tj], 0, 0, 0);
    }
  }

  // ---- epilogue: 2 slices of 64 rows via sO (aliases stage LDS) ----
  bool colFull = (colBlk + 128 <= N);
  #pragma unroll
  for (int s = 0; s < 2; ++s) {
    __syncthreads();   // s=0: all MFMA ds_reads done; s=1: slice-0 reads done
    if (wr == s) {
      #pragma unroll
      for (int ti = 0; ti < 4; ++ti)
        #pragma unroll
        for (int tj = 0; tj < 2; ++tj)
          #pragma unroll
          for (int qq = 0; qq < 4; ++qq)
            sO[(ti * 16 + kg * 4 + qq) * 133 + wc * 32 + tj * 16 + r16] = acc[ti][tj][qq];
    }
    __syncthreads();
    int srow0 = rowBlk + s * 64;
    #pragma unroll
    for (int p = 0; p < 4; ++p) {
      int i2 = p * 512 + tid;
      int row = i2 >> 5, c = i2 & 31;   // 32 lanes x 16B = 512 B per row segment
      f32x4 v = *(const f32x4*)&sO[row * 133 + c * 4];
      #pragma unroll
      for (int j = 0; j < 4; ++j) v[j] = 1.0f / (1.0f + __expf(-v[j]));
      int rr = srow0 + row;
      if (rr < N) {
        int col = colBlk + c * 4;
        if (colFull) {
          __builtin_nontemporal_store(v, (f32x4*)&out[(size_t)rr * N + col]);
        } else {
          #pragma unroll
          for (int j = 0; j < 4; ++j)
            if (col + j < N) __builtin_nontemporal_store(v[j], &out[(size_t)rr * N + col + j]);
        }
      }
    }
  }
}

// ---------------------------------------------------------------------------
extern "C" void kernel_launch(void* const* d_in, const int* in_sizes, int n_in,
                              void* d_out, int out_size, void* d_ws, size_t ws_size,
                              hipStream_t stream) {
  const float* x = (const float*)d_in[0];
  const int* ei = (const int*)d_in[1];
  const float* W = (const float*)d_in[2];
  const float* att_s = (const float*)d_in[3];
  const float* att_d = (const float*)d_in[4];
  const float* bias = (const float*)d_in[5];

  const int N = in_sizes[0] / IN_DIM;        // 10000
  const int E = in_sizes[1] / 2;             // 320000
  const int NB = (N + 127) / 128;            // 79
  const int NPAD = NB * 128;                 // 10112

  float* out = (float*)d_out;
  float* embed_out = out + (size_t)N * N;

  // workspace layout (all segments 16B-aligned)
  float* h = (float*)d_ws;                      // N*128 f32
  float* a_src = h + (size_t)N * OUT_DIM;       // N
  float* a_dst = a_src + N;                     // N
  int* cnt = (int*)(a_dst + N);                 // N
  int* row_start = cnt + N;                     // N+4 (padded)
  int* cursor = row_start + (N + 4);            // N
  int* csr = cursor + N;                        // E
  uint16_t* ebf = (uint16_t*)(csr + E);         // NPAD*128 bf16

  const int* e_src = ei;
  const int* e_dst = ei + E;

  hipMemsetAsync(cnt, 0, (size_t)N * sizeof(int), stream);
  k_h_gemm<<<dim3((N + 15) / 16), 256, 0, stream>>>(x, W, att_s, att_d,
                                                    e_dst, cnt, E, h, a_src, a_dst, N);
  k_scan<<<dim3(1), 1024, 0, stream>>>(cnt, row_start, cursor, N);
  k_fill<<<dim3((E + 255) / 256), 256, 0, stream>>>(e_src, e_dst, cursor, csr, E);
  k_aggregate<<<dim3((NPAD * 64 + 255) / 256), 256, 0, stream>>>(
      h, a_src, a_dst, row_start, csr, bias, embed_out, ebf, N, NPAD);
  k_recon<<<dim3(NB * NB), 512, 0, stream>>>(ebf, out, N, NB);
}

// Round 7
// 225.533 us; speedup vs baseline: 2.1582x; 1.0315x over previous
//
#include <hip/hip_runtime.h>
#include <stdint.h>

// ---------------------------------------------------------------------------
// StructureAE: h = x@W ; GAT edge softmax aggregate ; embed = leaky(out) ;
// recon = sigmoid(embed @ embed^T)
// N=10000, in_dim=512, out_dim=128, E=320000 (+N self loops)
// d_out = [recon (N*N f32), embed (N*128 f32)]
// ---------------------------------------------------------------------------

typedef __attribute__((ext_vector_type(8))) short short8v;  // 8 bf16 (4 VGPR)
typedef __attribute__((ext_vector_type(4))) float f32x4;

#define IN_DIM 512
#define OUT_DIM 128
#define NEG_ATT 0.5f
#define NEG_ACT 0.01f

__device__ __forceinline__ float leakyf(float v, float s) { return v >= 0.f ? v : s * v; }

__device__ __forceinline__ uint16_t f2bf(float v) {
  uint32_t u = __float_as_uint(v);
  u += 0x7FFFu + ((u >> 16) & 1u);   // round-to-nearest-even
  return (uint16_t)(u >> 16);
}
__device__ __forceinline__ float bf2f(uint16_t b) { return __uint_as_float(((uint32_t)b) << 16); }

// ---------------- h = x @ W (f32 compute, bf16 h store) + att dots + count --
// 16 rows/block, 625 blocks. tx = 32 col-groups x 4 f32; ty = 8 row-groups x
// 2 rows. W rows coalesced (L2-resident); x reads wave-broadcast.
// h stored as bf16 (h only feeds the aggregate gather; halves that traffic).
// Epilogue also counts this block's 512-edge slice into cnt (k_count fused).
__global__ __launch_bounds__(256) void k_h_gemm(const float* __restrict__ x,
                                                const float* __restrict__ W,
                                                const float* __restrict__ att_s_g,
                                                const float* __restrict__ att_d_g,
                                                const int* __restrict__ e_dst,
                                                int* __restrict__ cnt, int E,
                                                uint16_t* __restrict__ h16,
                                                float* __restrict__ a_src,
                                                float* __restrict__ a_dst, int N) {
  int tid = threadIdx.x;
  int tx = tid & 31, ty = tid >> 5;
  int row0 = blockIdx.x * 16 + ty * 2;
  int rc[2];
  #pragma unroll
  for (int r = 0; r < 2; ++r) rc[r] = (row0 + r < N) ? (row0 + r) : (N - 1);

  f32x4 acc[2];
  #pragma unroll
  for (int r = 0; r < 2; ++r) acc[r] = (f32x4){0.f, 0.f, 0.f, 0.f};

  for (int k = 0; k < IN_DIM; k += 4) {
    f32x4 wreg[4];
    #pragma unroll
    for (int kk = 0; kk < 4; ++kk)
      wreg[kk] = *(const f32x4*)&W[(size_t)(k + kk) * OUT_DIM + tx * 4];
    #pragma unroll
    for (int r = 0; r < 2; ++r) {
      f32x4 xv = *(const f32x4*)&x[(size_t)rc[r] * IN_DIM + k];
      #pragma unroll
      for (int kk = 0; kk < 4; ++kk) {
        acc[r][0] = fmaf(xv[kk], wreg[kk][0], acc[r][0]);
        acc[r][1] = fmaf(xv[kk], wreg[kk][1], acc[r][1]);
        acc[r][2] = fmaf(xv[kk], wreg[kk][2], acc[r][2]);
        acc[r][3] = fmaf(xv[kk], wreg[kk][3], acc[r][3]);
      }
    }
  }

  float atts[4], attd[4];
  #pragma unroll
  for (int j = 0; j < 4; ++j) { atts[j] = att_s_g[tx * 4 + j]; attd[j] = att_d_g[tx * 4 + j]; }
  #pragma unroll
  for (int r = 0; r < 2; ++r) {
    int row = row0 + r;
    float ps = 0.f, pd = 0.f;
    #pragma unroll
    for (int j = 0; j < 4; ++j) { ps = fmaf(acc[r][j], atts[j], ps); pd = fmaf(acc[r][j], attd[j], pd); }
    #pragma unroll
    for (int off = 16; off; off >>= 1) {   // reduce across the 32 tx lanes
      ps += __shfl_xor(ps, off);
      pd += __shfl_xor(pd, off);
    }
    if (row < N) {
      uint32_t lo = (uint32_t)f2bf(acc[r][0]) | ((uint32_t)f2bf(acc[r][1]) << 16);
      uint32_t hi = (uint32_t)f2bf(acc[r][2]) | ((uint32_t)f2bf(acc[r][3]) << 16);
      uint2 pk; pk.x = lo; pk.y = hi;
      *(uint2*)&h16[(size_t)row * OUT_DIM + tx * 4] = pk;
      if (tx == 0) { a_src[row] = ps; a_dst[row] = pd; }
    }
  }

  // fused edge counting (this block's 512-edge slice, coalesced)
  int e0 = blockIdx.x * 512 + tid;
  if (e0 < E) atomicAdd(&cnt[e_dst[e0]], 1);
  int e1 = e0 + 256;
  if (e1 < E) atomicAdd(&cnt[e_dst[e1]], 1);
}

// ---------------- CSR build --------------------------------------------------
__global__ __launch_bounds__(1024) void k_scan(const int* __restrict__ cnt,
                                               int* __restrict__ row_start,
                                               int* __restrict__ cursor, int N) {
  __shared__ int sd[1024];
  int t = threadIdx.x;
  const int CH = (N + 1023) >> 10;
  int base = t * CH;
  int s = 0;
  for (int k = 0; k < CH; ++k) { int i = base + k; if (i < N) s += cnt[i]; }
  sd[t] = s;
  __syncthreads();
  for (int off = 1; off < 1024; off <<= 1) {
    int v = (t >= off) ? sd[t - off] : 0;
    __syncthreads();
    sd[t] += v;
    __syncthreads();
  }
  int run = (t == 0) ? 0 : sd[t - 1];
  for (int k = 0; k < CH; ++k) {
    int i = base + k;
    if (i < N) { row_start[i] = run; cursor[i] = run; run += cnt[i]; }
  }
  if (t == 1023) row_start[N] = sd[1023];
}
__global__ void k_fill(const int* __restrict__ src, const int* __restrict__ dst,
                       int* __restrict__ cursor, int* __restrict__ csr, int E) {
  int e = blockIdx.x * blockDim.x + threadIdx.x;
  if (e < E) {
    int d = dst[e];
    int pos = atomicAdd(&cursor[d], 1);
    csr[pos] = src[e];
  }
}

// ---------------- per-dst softmax aggregation (one wave per node) -----------
// h gathered as bf16 (halved traffic). Waves i in [N, NPAD) zero ebf rows.
__global__ __launch_bounds__(256) void k_aggregate(
    const uint16_t* __restrict__ h16, const float* __restrict__ a_src,
    const float* __restrict__ a_dst, const int* __restrict__ row_start,
    const int* __restrict__ csr, const float* __restrict__ bias,
    float* __restrict__ embed_out, uint16_t* __restrict__ ebf, int N, int NPAD) {
  int wid = (int)((blockIdx.x * blockDim.x + threadIdx.x) >> 6);
  int lane = threadIdx.x & 63;
  if (wid >= N) {
    if (wid < NPAD) {
      ebf[(size_t)wid * OUT_DIM + lane] = 0;
      ebf[(size_t)wid * OUT_DIM + 64 + lane] = 0;
    }
    return;
  }
  int i = wid;
  int s0 = row_start[i], s1 = row_start[i + 1];
  float adst = a_dst[i];
  float eself = leakyf(a_src[i] + adst, NEG_ATT);
  float m = eself;
  for (int k = s0 + lane; k < s1; k += 64) {
    float e = leakyf(a_src[csr[k]] + adst, NEG_ATT);
    m = fmaxf(m, e);
  }
  #pragma unroll
  for (int off = 32; off; off >>= 1) m = fmaxf(m, __shfl_xor(m, off));
  float dsum = 0.f;
  for (int k = s0 + lane; k < s1; k += 64) {
    float e = leakyf(a_src[csr[k]] + adst, NEG_ATT);
    dsum += __expf(e - m);
  }
  #pragma unroll
  for (int off = 32; off; off >>= 1) dsum += __shfl_xor(dsum, off);
  dsum += __expf(eself - m);
  float inv = 1.0f / dsum;
  float wself = __expf(eself - m) * inv;
  float acc0 = bf2f(h16[(size_t)i * OUT_DIM + lane]) * wself;
  float acc1 = bf2f(h16[(size_t)i * OUT_DIM + 64 + lane]) * wself;
  #pragma unroll 4
  for (int k = s0; k < s1; ++k) {
    int s = csr[k];  // uniform across wave
    float w = __expf(leakyf(a_src[s] + adst, NEG_ATT) - m) * inv;
    acc0 = fmaf(bf2f(h16[(size_t)s * OUT_DIM + lane]), w, acc0);
    acc1 = fmaf(bf2f(h16[(size_t)s * OUT_DIM + 64 + lane]), w, acc1);
  }
  float o0 = leakyf(acc0 + bias[lane], NEG_ACT);
  float o1 = leakyf(acc1 + bias[64 + lane], NEG_ACT);
  embed_out[(size_t)i * OUT_DIM + lane] = o0;
  embed_out[(size_t)i * OUT_DIM + 64 + lane] = o1;
  ebf[(size_t)i * OUT_DIM + lane] = f2bf(o0);
  ebf[(size_t)i * OUT_DIM + 64 + lane] = f2bf(o1);
}

// ---------------- recon = sigmoid(embed @ embed^T), LDS-staged MFMA ---------
// 128x128 tile, 512 thr = 8 waves (2 row x 4 col), wave = 64x32.
// 48 KB LDS (sA 32 KB full tile; sB 16 KB = K-half, restaged mid-loop) ->
// 3 blocks/CU (24 waves/CU): store bursts of one block overlap compute/stage
// of the other two -> higher write-pipe duty (round-6 limiter).
// Epilogue slab sO aliases sA (stride 128 f32 + slot^(kg<<1) swizzle, worst
// 2-way = free). Stores: 512 B contiguous nontemporal row segments.
// mfma_f32_16x16x32_bf16 A/B: lane holds row/col = lane&15, k = 8*(lane>>4)+j;
// C/D: col = lane&15, row = (lane>>4)*4 + reg.
__global__ __launch_bounds__(512, 6) void k_recon(const uint16_t* __restrict__ ebf,
                                                  float* __restrict__ out,
                                                  int N, int nb) {
  __shared__ __align__(16) unsigned char smem[49152];
  uint16_t* sA = (uint16_t*)smem;            // [128][128] bf16, swizzled
  uint16_t* sB = (uint16_t*)(smem + 32768);  // [128][64] bf16 (K-half), swizzled
  float* sO = (float*)smem;                  // [64][128] f32 (aliases sA)

  int tid = threadIdx.x;
  int wid = tid >> 6, lane = tid & 63;
  int wr = wid >> 2, wc = wid & 3;
  int r16 = lane & 15, kg = lane >> 4;

  // bijective XCD swizzle (m204): per-XCD contiguous tile range,
  // row-panel-major; B panel (2.6 MB) stays L2-resident per XCD.
  int nwg = nb * nb;
  int q = nwg >> 3, r8 = nwg & 7;
  int orig = blockIdx.x;
  int xcd = orig & 7, sub = orig >> 3;
  int swz = (xcd < r8 ? xcd * (q + 1) : r8 * (q + 1) + (xcd - r8) * q) + sub;
  int by = swz / nb, bx = swz - by * nb;
  int rowBlk = by * 128, colBlk = bx * 128;

  // ---- stage A tile (full K) + B tile K-half 0 ----
  #pragma unroll
  for (int p = 0; p < 4; ++p) {
    int i2 = p * 512 + tid;          // 2048 x 16B chunks
    int row = i2 >> 4, slot = i2 & 15;
    f32x4 va = *(const f32x4*)&ebf[(size_t)(rowBlk + row) * OUT_DIM + slot * 8];
    int ss = slot ^ (row & 7);
    *(f32x4*)&sA[row * OUT_DIM + ss * 8] = va;
  }
  #pragma unroll
  for (int p = 0; p < 2; ++p) {
    int i2 = p * 512 + tid;          // 1024 x 16B chunks
    int row = i2 >> 3, slot = i2 & 7;
    f32x4 vb = *(const f32x4*)&ebf[(size_t)(colBlk + row) * OUT_DIM + slot * 8];
    int ss = slot ^ (row & 7);
    *(f32x4*)&sB[row * 64 + ss * 8] = vb;
  }
  __syncthreads();

  // ---- MFMA: wave computes 64x32; K=128 as 2 halves x 2 chunks of 32 ----
  int rowWl = wr * 64, colWl = wc * 32;
  f32x4 acc[4][2];
  #pragma unroll
  for (int a = 0; a < 4; ++a)
    #pragma unroll
    for (int b = 0; b < 2; ++b) acc[a][b] = (f32x4){0.f, 0.f, 0.f, 0.f};

  #pragma unroll
  for (int half = 0; half < 2; ++half) {
    #pragma unroll
    for (int kch = 0; kch < 2; ++kch) {
      int s16 = (half * 2 + kch) * 4 + kg;   // absolute K-slot for A (0..15)
      int khalf = kch * 4 + kg;              // within-half K-slot for B (0..7)
      short8v bfr[2];
      #pragma unroll
      for (int tj = 0; tj < 2; ++tj) {
        int rw = colWl + tj * 16 + r16;
        int ss = khalf ^ (rw & 7);
        bfr[tj] = *(const short8v*)&sB[rw * 64 + ss * 8];
      }
      #pragma unroll
      for (int ti = 0; ti < 4; ++ti) {
        int rw = rowWl + ti * 16 + r16;
        int ss = s16 ^ (rw & 7);
        short8v af = *(const short8v*)&sA[rw * OUT_DIM + ss * 8];
        #pragma unroll
        for (int tj = 0; tj < 2; ++tj)
          acc[ti][tj] = __builtin_amdgcn_mfma_f32_16x16x32_bf16(af, bfr[tj], acc[ti][tj], 0, 0, 0);
      }
    }
    if (half == 0) {   // restage B with K-half 1
      __syncthreads();
      #pragma unroll
      for (int p = 0; p < 2; ++p) {
        int i2 = p * 512 + tid;
        int row = i2 >> 3, slot = i2 & 7;
        f32x4 vb = *(const f32x4*)&ebf[(size_t)(colBlk + row) * OUT_DIM + 64 + slot * 8];
        int ss = slot ^ (row & 7);
        *(f32x4*)&sB[row * 64 + ss * 8] = vb;
      }
      __syncthreads();
    }
  }
  __syncthreads();   // sA reads done; safe to overwrite via sO

  // ---- epilogue: 2 slices of 64 rows via sO (aliases sA region) ----
  bool colFull = (colBlk + 128 <= N);
  #pragma unroll
  for (int s = 0; s < 2; ++s) {
    if (wr == s) {
      #pragma unroll
      for (int ti = 0; ti < 4; ++ti)
        #pragma unroll
        for (int tj = 0; tj < 2; ++tj) {
          int col = wc * 32 + tj * 16 + r16;
          int slot = col >> 2, within = col & 3;
          int sslot = slot ^ (kg << 1);
          #pragma unroll
          for (int qq = 0; qq < 4; ++qq)
            sO[(ti * 16 + kg * 4 + qq) * 128 + sslot * 4 + within] = acc[ti][tj][qq];
        }
    }
    __syncthreads();
    int srow0 = rowBlk + s * 64;
    #pragma unroll
    for (int p = 0; p < 4; ++p) {
      int i2 = p * 512 + tid;
      int row = i2 >> 5, c = i2 & 31;   // 32 lanes x 16B = 512 B per row segment
      int sslot = c ^ (((row >> 2) & 3) << 1);
      f32x4 v = *(const f32x4*)&sO[row * 128 + sslot * 4];
      #pragma unroll
      for (int j = 0; j < 4; ++j) v[j] = 1.0f / (1.0f + __expf(-v[j]));
      int rr = srow0 + row;
      if (rr < N) {
        int col = colBlk + c * 4;
        if (colFull) {
          __builtin_nontemporal_store(v, (f32x4*)&out[(size_t)rr * N + col]);
        } else {
          #pragma unroll
          for (int j = 0; j < 4; ++j)
            if (col + j < N) __builtin_nontemporal_store(v[j], &out[(size_t)rr * N + col + j]);
        }
      }
    }
    if (s == 0) __syncthreads();   // slice-0 reads done before slice-1 deposit
  }
}

// ---------------------------------------------------------------------------
extern "C" void kernel_launch(void* const* d_in, const int* in_sizes, int n_in,
                              void* d_out, int out_size, void* d_ws, size_t ws_size,
                              hipStream_t stream) {
  const float* x = (const float*)d_in[0];
  const int* ei = (const int*)d_in[1];
  const float* W = (const float*)d_in[2];
  const float* att_s = (const float*)d_in[3];
  const float* att_d = (const float*)d_in[4];
  const float* bias = (const float*)d_in[5];

  const int N = in_sizes[0] / IN_DIM;        // 10000
  const int E = in_sizes[1] / 2;             // 320000
  const int NB = (N + 127) / 128;            // 79
  const int NPAD = NB * 128;                 // 10112

  float* out = (float*)d_out;
  float* embed_out = out + (size_t)N * N;

  // workspace layout (all segments 16B-aligned)
  uint16_t* h16 = (uint16_t*)d_ws;              // N*128 bf16
  float* a_src = (float*)(h16 + (size_t)N * OUT_DIM);  // N
  float* a_dst = a_src + N;                     // N
  int* cnt = (int*)(a_dst + N);                 // N
  int* row_start = cnt + N;                     // N+4 (padded)
  int* cursor = row_start + (N + 4);            // N
  int* csr = cursor + N;                        // E
  uint16_t* ebf = (uint16_t*)(csr + E);         // NPAD*128 bf16

  const int* e_src = ei;
  const int* e_dst = ei + E;

  hipMemsetAsync(cnt, 0, (size_t)N * sizeof(int), stream);
  k_h_gemm<<<dim3((N + 15) / 16), 256, 0, stream>>>(x, W, att_s, att_d,
                                                    e_dst, cnt, E, h16, a_src, a_dst, N);
  k_scan<<<dim3(1), 1024, 0, stream>>>(cnt, row_start, cursor, N);
  k_fill<<<dim3((E + 255) / 256), 256, 0, stream>>>(e_src, e_dst, cursor, csr, E);
  k_aggregate<<<dim3((NPAD * 64 + 255) / 256), 256, 0, stream>>>(
      h16, a_src, a_dst, row_start, csr, bias, embed_out, ebf, N, NPAD);
  k_recon<<<dim3(NB * NB), 512, 0, stream>>>(ebf, out, N, NB);
}